// Round 2
// baseline (240.311 us; speedup 1.0000x reference)
//
#include <hip/hip_runtime.h>

// Batched 16x16 Sinkhorn (VotingLayer) via scaling vectors.
// S_t = diag(r) * S0 * diag(c), S0 = v_matrix^T + 1e-6.
// Per iteration:  c = 1/(S0^T r)  (column sums),  r = 1/(S0 c)  (row sums).
// Final output: diag(r) * S0 * diag(c).
//
// 4 lanes per matrix (one quad). Lane c owns global columns 4c..4c+3 of S0
// (= rows 4c..4c+3 of the v matrix: 64 contiguous floats).
// Column phase: lane-local (full 16-row sums in-register, 4 distinct rcps).
// Row phase: per-lane partial over its 4 columns, quad_perm DPP all-reduce,
// 16 (quad-redundant) rcps.
// All FMAs packed via float2 ext-vectors -> v_pk_fma_f32.

#define NITER 10
typedef float v2f __attribute__((ext_vector_type(2)));

template <int CTRL>
__device__ __forceinline__ float dpp_add(float x) {
    int xi = __builtin_bit_cast(int, x);
    int yi = __builtin_amdgcn_update_dpp(xi, xi, CTRL, 0xF, 0xF, false);
    return x + __builtin_bit_cast(float, yi);
}

__device__ __forceinline__ float qsum(float x) {  // all-reduce over a quad
    x = dpp_add<0xB1>(x);   // quad_perm [1,0,3,2]  (xor 1)
    x = dpp_add<0x4E>(x);   // quad_perm [2,3,0,1]  (xor 2)
    return x;
}

__global__ __launch_bounds__(256) void sinkhorn16_kernel(
        const float* __restrict__ v, float* __restrict__ out, int nmat) {
    const int tid = blockIdx.x * 256 + threadIdx.x;
    const int b   = tid >> 2;
    if (b >= nmat) return;
    const int c   = tid & 3;

    // Lane's 64 floats are contiguous: v[b][4c+0..4c+3][0..15].
    const float* base = v + (size_t)b * 256 + c * 64;
    // col[j][i2] = (S0[2*i2][4c+j], S0[2*i2+1][4c+j])
    v2f col[4][8];
#pragma unroll
    for (int j = 0; j < 4; ++j) {
#pragma unroll
        for (int g = 0; g < 4; ++g) {
            float4 f = *(const float4*)(base + j * 16 + g * 4);
            col[j][2 * g]     = (v2f){f.x + 1e-6f, f.y + 1e-6f};
            col[j][2 * g + 1] = (v2f){f.z + 1e-6f, f.w + 1e-6f};
        }
    }

    v2f rv[8];
#pragma unroll
    for (int i2 = 0; i2 < 8; ++i2) rv[i2] = (v2f){1.0f, 1.0f};
    float cj[4];

#pragma unroll
    for (int it = 0; it < NITER; ++it) {
        // ---- c = 1/(S0^T r): lane-local over its 4 columns ----
#pragma unroll
        for (int j = 0; j < 4; ++j) {
            v2f acc = col[j][0] * rv[0];
#pragma unroll
            for (int i2 = 1; i2 < 8; ++i2) acc += col[j][i2] * rv[i2];
            cj[j] = __builtin_amdgcn_rcpf(acc.x + acc.y);
        }
        // ---- r = 1/(S0 c): partial over own columns, quad all-reduce ----
#pragma unroll
        for (int i2 = 0; i2 < 8; ++i2) {
            v2f p =  col[0][i2] * (v2f){cj[0], cj[0]};
            p     += col[1][i2] * (v2f){cj[1], cj[1]};
            p     += col[2][i2] * (v2f){cj[2], cj[2]};
            p     += col[3][i2] * (v2f){cj[3], cj[3]};
            rv[i2].x = __builtin_amdgcn_rcpf(qsum(p.x));
            rv[i2].y = __builtin_amdgcn_rcpf(qsum(p.y));
        }
    }

    // ---- epilogue: out[i][4c+j] = r[i] * S0[i][4c+j] * c[4c+j] ----
    float* ob = out + (size_t)b * 256 + c * 4;
#pragma unroll
    for (int i2 = 0; i2 < 8; ++i2) {
        v2f s0 = col[0][i2] * rv[i2];
        v2f s1 = col[1][i2] * rv[i2];
        v2f s2 = col[2][i2] * rv[i2];
        v2f s3 = col[3][i2] * rv[i2];
        *(float4*)(ob + (2 * i2) * 16) =
            make_float4(s0.x * cj[0], s1.x * cj[1], s2.x * cj[2], s3.x * cj[3]);
        *(float4*)(ob + (2 * i2 + 1) * 16) =
            make_float4(s0.y * cj[0], s1.y * cj[1], s2.y * cj[2], s3.y * cj[3]);
    }
}

extern "C" void kernel_launch(void* const* d_in, const int* in_sizes, int n_in,
                              void* d_out, int out_size, void* d_ws, size_t ws_size,
                              hipStream_t stream) {
    const float* v = (const float*)d_in[0];
    float* out = (float*)d_out;
    const int nmat = in_sizes[0] >> 8;           // 131072
    const int total_threads = nmat * 4;          // 4 lanes per matrix
    const int block = 256;
    const int grid = (total_threads + block - 1) / block;  // 2048
    sinkhorn16_kernel<<<grid, block, 0, stream>>>(v, out, nmat);
}

// Round 3
// 230.966 us; speedup vs baseline: 1.0405x; 1.0405x over previous
//
#include <hip/hip_runtime.h>

// Batched 16x16 Sinkhorn (VotingLayer) via scaling vectors, 16 lanes/matrix.
// S_t = diag(r) * S0 * diag(c), S0 = v_matrix^T + 1e-6.
// Per iteration:  c = 1/(S0^T r)  (column sums),  r = 1/(S0 c)  (row sums).
// Output: diag(r) * S0 * diag(c).
//
// Lane idx (0..15): r-group = idx&3, c-group = idx>>2; lane owns the 4x4 block
//   blk[i][j] = S0[4r+i][4c+j] = v[b][4c+j][4r+i]   (transpose = reg naming).
// Column phase: 4-row partials in-lane, quad_perm DPP allreduce (xor lane bits
// 0-1 = same-column lanes), 4 rcp. Row phase: 4-col partials in-lane,
// row_ror:4/8 DPP allreduce (same-row lanes), 4 rcp. Matrix never updated.
// Packed v_pk_fma_f32 along the j (column) axis.

#define NITER 10
typedef float v2f __attribute__((ext_vector_type(2)));

template <int CTRL>
__device__ __forceinline__ float dpp_add(float x) {
    int xi = __builtin_bit_cast(int, x);
    int yi = __builtin_amdgcn_update_dpp(xi, xi, CTRL, 0xF, 0xF, false);
    return x + __builtin_bit_cast(float, yi);
}

__global__ __launch_bounds__(256) void sinkhorn16_kernel(
        const float* __restrict__ v, float* __restrict__ out, int nmat) {
    const int tid = blockIdx.x * 256 + threadIdx.x;
    const int b   = tid >> 4;
    if (b >= nmat) return;
    const int idx = tid & 15;
    const int r   = idx & 3;
    const int c   = idx >> 2;

    // fj[j] = v[b][4c+j][4r+0..3] = (blk[0][j], blk[1][j], blk[2][j], blk[3][j])
    const float* base = v + (size_t)b * 256 + c * 64 + r * 4;
    float4 fj[4];
#pragma unroll
    for (int j = 0; j < 4; ++j) fj[j] = *(const float4*)(base + 16 * j);

    // bp[i][j2] = (blk[i][2*j2], blk[i][2*j2+1]) + 1e-6
    v2f bp[4][2];
#pragma unroll
    for (int j2 = 0; j2 < 2; ++j2) {
        const float4 fa = fj[2 * j2], fb = fj[2 * j2 + 1];
        bp[0][j2] = (v2f){fa.x + 1e-6f, fb.x + 1e-6f};
        bp[1][j2] = (v2f){fa.y + 1e-6f, fb.y + 1e-6f};
        bp[2][j2] = (v2f){fa.z + 1e-6f, fb.z + 1e-6f};
        bp[3][j2] = (v2f){fa.w + 1e-6f, fb.w + 1e-6f};
    }

    float rv[4] = {1.0f, 1.0f, 1.0f, 1.0f};
    v2f cjp[2];

#pragma unroll
    for (int it = 0; it < NITER; ++it) {
        // ---- column phase: c_j = 1/sum_i S0[i][j]*r_i ----
#pragma unroll
        for (int j2 = 0; j2 < 2; ++j2) {
            v2f acc = bp[0][j2] * (v2f){rv[0], rv[0]};
            acc += bp[1][j2] * (v2f){rv[1], rv[1]};
            acc += bp[2][j2] * (v2f){rv[2], rv[2]};
            acc += bp[3][j2] * (v2f){rv[3], rv[3]};
            // allreduce over same-column lanes (lane bits 0-1)
            float s0 = dpp_add<0x4E>(dpp_add<0xB1>(acc.x));
            float s1 = dpp_add<0x4E>(dpp_add<0xB1>(acc.y));
            cjp[j2] = (v2f){__builtin_amdgcn_rcpf(s0), __builtin_amdgcn_rcpf(s1)};
        }
        // ---- row phase: r_i = 1/sum_j S0[i][j]*c_j ----
#pragma unroll
        for (int i = 0; i < 4; ++i) {
            v2f t = bp[i][0] * cjp[0] + bp[i][1] * cjp[1];
            // allreduce over same-row lanes (lane bits 2-3)
            float s = dpp_add<0x128>(dpp_add<0x124>(t.x + t.y));
            rv[i] = __builtin_amdgcn_rcpf(s);
        }
    }

    // ---- epilogue: out[4r+i][4c+j] = blk[i][j] * rv[i] * c_j ----
    float* ob = out + (size_t)b * 256 + r * 64 + c * 4;
#pragma unroll
    for (int i = 0; i < 4; ++i) {
        const v2f rvp = (v2f){rv[i], rv[i]};
        const v2f s0 = bp[i][0] * cjp[0] * rvp;
        const v2f s1 = bp[i][1] * cjp[1] * rvp;
        *(float4*)(ob + 16 * i) = make_float4(s0.x, s0.y, s1.x, s1.y);
    }
}

extern "C" void kernel_launch(void* const* d_in, const int* in_sizes, int n_in,
                              void* d_out, int out_size, void* d_ws, size_t ws_size,
                              hipStream_t stream) {
    const float* v = (const float*)d_in[0];
    float* out = (float*)d_out;
    const int nmat = in_sizes[0] >> 8;            // 131072
    const int total_threads = nmat * 16;          // 16 lanes per matrix
    const int block = 256;
    const int grid = (total_threads + block - 1) / block;  // 8192
    sinkhorn16_kernel<<<grid, block, 0, stream>>>(v, out, nmat);
}